// Round 2
// baseline (532.247 us; speedup 1.0000x reference)
//
#include <hip/hip_runtime.h>

// Problem constants (from reference setup_inputs)
#define BB 8      // batch
#define RR 16     // rotations
#define NN 6144   // gpc systems (vertices)
#define FF 128    // features

typedef float f32x4 __attribute__((ext_vector_type(4)));

// Norm scratch, [B][N][R] layout so pass-2 reads 16 norms contiguously (64 B).
// 8*6144*16*4 = 3 MB static device global — avoids any dependence on ws_size.
__device__ float g_norms[(size_t)BB * NN * RR];

// ---------------------------------------------------------------------------
// Pass 1 — pure streaming norm computation.
// A "chunk" = 4 consecutive rows = 2 KB of input. Quarter-wave (16 lanes) per
// row, identical summation order to the previously-passing kernel (8 squares
// per lane, xor 1/2/4/8 butterfly) so results are bit-identical.
// Chunk index = wave + i*P1_WAVES: at any instant the active waves cover a
// dense sliding ~24 MB window in ascending address order — linear DRAM
// stream, unlike the old per-wave 3MB-stride walk over 16 rotation planes.
// ---------------------------------------------------------------------------
#define P1_WAVES 12288                 // (BB*RR*NN/4) / P1_ITERS
#define P1_ITERS 16

__global__ __launch_bounds__(256) void norm_kernel(const float* __restrict__ in) {
    const int tid     = blockIdx.x * 256 + threadIdx.x;
    const int wave    = tid >> 6;
    const int lane    = tid & 63;
    const int quarter = lane >> 4;
    const int sublane = lane & 15;

    #pragma unroll 4
    for (int i = 0; i < P1_ITERS; ++i) {
        const int chunk = wave + i * P1_WAVES;     // [0, BB*RR*NN/4)
        const int g     = chunk * 4 + quarter;     // global row = (b*RR+r)*NN + n
        const float* p  = in + (size_t)g * FF + (sublane << 2);
        const f32x4 va  = *(const f32x4*)p;
        const f32x4 vb  = *(const f32x4*)(p + 64);
        float s = va.x * va.x + va.y * va.y + va.z * va.z + va.w * va.w
                + vb.x * vb.x + vb.y * vb.y + vb.z * vb.z + vb.w * vb.w;
        // 16-lane butterfly sum (stays within each quarter of the wave)
        s += __shfl_xor(s, 1);
        s += __shfl_xor(s, 2);
        s += __shfl_xor(s, 4);
        s += __shfl_xor(s, 8);
        if (sublane == 0) {
            const int n  = g % NN;                 // row decompose
            const int br = g / NN;                 // b*RR + r
            const int r  = br & (RR - 1);
            const int b  = br >> 4;                // RR = 16
            g_norms[((size_t)(b * NN + n) << 4) + r] = s;
        }
    }
}

// ---------------------------------------------------------------------------
// Pass 2 — argmax over R (16 lanes, min-index tie-break == jnp.argmax) and
// gather of the winning 512 B row. Norm reads are fully coalesced (wave reads
// 256 B contiguous); gather reads are 512 B segments; output stores are
// nontemporal (never re-read).
// ---------------------------------------------------------------------------
__global__ __launch_bounds__(256) void gather_kernel(const float* __restrict__ in,
                                                     float* __restrict__ out) {
    const int tid     = blockIdx.x * 256 + threadIdx.x;
    const int wave    = tid >> 6;
    const int lane    = tid & 63;
    const int quarter = lane >> 4;
    const int sublane = lane & 15;

    const int j = wave * 4 + quarter;              // (b*NN + n) in [0, BB*NN)

    // lane 'sublane' holds the norm for rotation r = sublane
    float s  = g_norms[((size_t)j << 4) + sublane];
    int   idx = sublane;
    #pragma unroll
    for (int m = 1; m < 16; m <<= 1) {
        const float so = __shfl_xor(s, m);
        const int   io = __shfl_xor(idx, m);
        const bool take = (so > s) || ((so == s) && (io < idx));
        s   = take ? so : s;
        idx = take ? io : idx;                     // lowest-index max, all 16 lanes agree
    }

    const int b = j / NN;
    const int n = j - b * NN;

    const float* q = in + (((size_t)(b * RR + idx)) * NN + n) * (size_t)FF + (sublane << 2);
    const f32x4 wa = *(const f32x4*)q;
    const f32x4 wb = *(const f32x4*)(q + 64);

    float* o = out + (size_t)j * FF + (sublane << 2);
    __builtin_nontemporal_store(wa, (f32x4*)o);
    __builtin_nontemporal_store(wb, (f32x4*)(o + 64));
}

extern "C" void kernel_launch(void* const* d_in, const int* in_sizes, int n_in,
                              void* d_out, int out_size, void* d_ws, size_t ws_size,
                              hipStream_t stream) {
    const float* in  = (const float*)d_in[0];
    float*       out = (float*)d_out;

    // Pass 1: 12288 waves x 16 chunks = 196608 chunks = full 403 MB input
    norm_kernel<<<dim3(P1_WAVES / 4), dim3(256), 0, stream>>>(in);

    // Pass 2: BB*NN/4 = 12288 waves, 4 waves per block
    const int p2_blocks = (BB * NN / 4) / 4;       // 3072
    gather_kernel<<<dim3(p2_blocks), dim3(256), 0, stream>>>(in, out);
}

// Round 3
// 493.113 us; speedup vs baseline: 1.0794x; 1.0794x over previous
//
#include <hip/hip_runtime.h>

// Problem constants (from reference setup_inputs)
#define BB 8      // batch
#define RR 16     // rotations
#define NN 6144   // gpc systems (vertices)
#define FF 128    // features

// Native clang vector type — required for __builtin_nontemporal_load/store.
typedef float f32x4 __attribute__((ext_vector_type(4)));

// Quarter-wave (16 lanes) per (b, n) row; one wave handles 4 consecutive rows.
// Each lane owns 8 features, split as two coalesced dwordx4 groups:
//   group A: features [sublane*4 .. sublane*4+4)        (row bytes   0..255)
//   group B: features [64 + sublane*4 .. 64+sublane*4+4) (row bytes 256..511)
// Per rotation: 2 coalesced 16B/lane loads (2 KB / wave), per-lane sum of 8
// squares, 4-level butterfly (xor 1,2,4,8 — stays inside each 16-lane
// quarter), keep running-best 8 floats in registers.
// Strict '>' keeps the FIRST max (matches jnp.argmax tie-break).
//
// NOTE (session journal): this is the previous session's best kernel,
// reverted verbatim. Round-1 (unroll 4, cached loads, argmax+reload,
// launch_bounds(256,8)) = 523 us; Round-2 (two-pass linear stream) = 532 us.
// Counter analysis says dur_us = ~494 us of workspace re-poison fills
// (2 x 247 us, 1.5 GiB each at 6.5 TB/s) + kernel; this kernel's own cost
// is O(30 us) thanks to steady-state L3 residency of the 403 MB input.
__global__ __launch_bounds__(256) void amp_kernel(const float* __restrict__ in,
                                                  float* __restrict__ out) {
    const int tid     = blockIdx.x * 256 + threadIdx.x;
    const int wave    = tid >> 6;        // global wave id = group of 4 rows
    const int lane    = tid & 63;
    const int quarter = lane >> 4;       // 0..3: which row within the wave
    const int sublane = lane & 15;       // feature group within row

    const int b     = wave / (NN / 4);
    const int n_grp = wave - b * (NN / 4);
    const int n     = n_grp * 4 + quarter;

    // &in[b][0][n][sublane*4]
    const size_t base    = (((size_t)b * RR) * NN + n) * (size_t)FF + (sublane << 2);
    const size_t rstride = (size_t)NN * FF;   // stride between rotations

    f32x4 best_a   = (f32x4)(0.f);
    f32x4 best_b   = (f32x4)(0.f);
    float best_sum = -1.f;                    // norms >= 0, so r=0 always wins first

    #pragma unroll
    for (int r = 0; r < RR; ++r) {
        const float* p = in + base + (size_t)r * rstride;
        const f32x4 va = __builtin_nontemporal_load((const f32x4*)p);
        const f32x4 vb = __builtin_nontemporal_load((const f32x4*)(p + 64));
        float s = va.x * va.x + va.y * va.y + va.z * va.z + va.w * va.w
                + vb.x * vb.x + vb.y * vb.y + vb.z * vb.z + vb.w * vb.w;
        // 16-lane butterfly sum (stays within each quarter of the wave)
        s += __shfl_xor(s, 1);
        s += __shfl_xor(s, 2);
        s += __shfl_xor(s, 4);
        s += __shfl_xor(s, 8);
        if (s > best_sum) {                   // strict: first max wins, like argmax
            best_sum = s;
            best_a   = va;
            best_b   = vb;
        }
    }

    // &out[b][n][sublane*4]
    float* o = out + ((size_t)b * NN + n) * (size_t)FF + (sublane << 2);
    __builtin_nontemporal_store(best_a, (f32x4*)o);
    __builtin_nontemporal_store(best_b, (f32x4*)(o + 64));
}

extern "C" void kernel_launch(void* const* d_in, const int* in_sizes, int n_in,
                              void* d_out, int out_size, void* d_ws, size_t ws_size,
                              hipStream_t stream) {
    const float* in  = (const float*)d_in[0];
    float*       out = (float*)d_out;

    // B*N/4 waves (each wave does 4 rows), 4 waves (256 threads) per block
    const int n_waves  = BB * NN / 4;         // 12288
    const int n_blocks = n_waves / 4;         // 3072

    amp_kernel<<<dim3(n_blocks), dim3(256), 0, stream>>>(in, out);
}